// Round 6
// baseline (92.604 us; speedup 1.0000x reference)
//
#include <hip/hip_runtime.h>
#include <math.h>

#define L_TOT   589      // int(round(fp32(49*1.2f)/0.1))+1
#define L_PAD   592      // pad to 8-multiple with zeros (after last sample idx)
#define NCHUNK  (L_PAD / 8)   // 74
#define NDELAY  30
#define NSAMP   50
#define HW_PIX  102400   // 320*320
#define STEPF   0.1f
#define BLK     64

__device__ __forceinline__ float frcp(float x) { return __builtin_amdgcn_rcpf(x); }

// Prep (1 block): AIF = linear interp of Cp onto 0.1s grid delayed 30 steps
// (zeros pad to 592), and searchsorted sample indices. Written to d_ws.
__global__ void prep_kernel(const float* __restrict__ st,
                            const float* __restrict__ Cp,
                            float* __restrict__ aif,
                            int* __restrict__ idx)
{
    __shared__ float s_st[NSAMP], s_cp[NSAMP];
    const int k = threadIdx.x;
    if (k < NSAMP) { s_st[k] = st[k]; s_cp[k] = Cp[k]; }
    __syncthreads();

    if (k < L_PAD) {
        float v = 0.0f;
        if (k >= NDELAY && k < L_TOT) {
            float t = (float)(k - NDELAY) * STEPF;   // == t_samp[k-30] bitwise
            int j = (k - NDELAY) / 12;               // st spacing 1.2 s = 12 steps
            if (j > NSAMP - 2) j = NSAMP - 2;
            if (s_st[j + 1] <= t) ++j;               // exact-fp32 boundary fixups
            if (j > 0 && s_st[j] > t) --j;
            v = s_cp[j] + (t - s_st[j]) * (s_cp[j + 1] - s_cp[j])
                        / (s_st[j + 1] - s_st[j]);
        }
        aif[k] = v;
    }
    // searchsorted(t_samp, sample_time, 'left'), exact fp32, gather-clamped
    if (k < NSAMP) {
        float sv = s_st[k];
        int lo = 12 * k - 2; if (lo < 0) lo = 0;
        int cnt = lo;
        for (int n = lo; n <= 12 * k + 2; ++n)
            if ((float)n * STEPF < sv) cnt = n + 1;   // monotone predicate
        idx[k] = min(cnt, L_TOT - 1);
    }
}

// Main: one thread per pixel, two exponential-convolution recurrences
// (FFT conv of the 2-exp impulse response == S_n = r*S_{n-1} + aif[n]).
// AIF read straight from global (2.4 KB, wave-uniform -> L1-resident), no LDS,
// no syncthreads. float4 chunks with prefetch distance 2; emission index
// double-buffered (next/next2) so its load latency hides behind a segment.
__global__ __launch_bounds__(BLK) void dce_kernel(
    const float* __restrict__ param,
    const float* __restrict__ aif_g,   // L_PAD floats in d_ws
    const int*   __restrict__ idx_g,   // NSAMP ints in d_ws
    float* __restrict__ out,           // fp32 output
    float M0_trans, float cos_fa, float sig_base)
{
    const int pix = blockIdx.x * BLK + threadIdx.x;
    const float ve = param[0 * HW_PIX + pix];
    const float vp = param[1 * HW_PIX + pix];
    const float fp = param[2 * HW_PIX + pix];
    const float ps = param[3 * HW_PIX + pix];

    // params in [0.05,1] => all finite/positive; reference _nan0 never fires.
    // v_rcp_f32 (~1 ulp) in place of IEEE divide: rel err ~1e-7, harmless
    // against the 2% absolute tolerance.
    const float Te   = ve * frcp(ps);
    const float rfp  = frcp(fp);
    const float T    = (vp + ve) * rfp;
    const float Tc   = vp * rfp;
    const float sm   = T + Te;
    const float disc = sqrtf(sm * sm - 4.0f * Tc * Te);
    const float rd2  = frcp(2.0f * Tc * Te);
    const float thp  = (sm + disc) * rd2;
    const float thm  = (sm - disc) * rd2;

    const float rm = __expf(-STEPF * thm);
    const float rp = __expf(-STEPF * thp);

    // normalizers: geometric sums over the 589-point grid (1-rm >= 1.6e-3)
    const float Se = (1.0f - __expf(-(STEPF * (float)L_TOT) * thm)) * frcp(1.0f - rm);
    const float Sp = (1.0f - __expf(-(STEPF * (float)L_TOT) * thp)) * frcp(1.0f - rp);

    const float we  = 1.0f - Te * thm;   // > 0
    const float wpp = Te * thp - 1.0f;   // > 0
    const float inv_De = frcp(Se - Sp);             // Se > Sp strictly
    const float inv_Dp = frcp(we * Se + wpp * Sp);  // > 0 strictly

    float Sm = 0.0f, Spv = 0.0f;
    int s = 0;
    int next  = __builtin_amdgcn_readfirstlane(idx_g[0]);
    int next2 = __builtin_amdgcn_readfirstlane(idx_g[1]);

    const float4* aif4 = (const float4*)aif_g;
    float4 c0 = aif4[0], c1 = aif4[1];   // current chunk (8 steps)
    float4 n0 = aif4[2], n1 = aif4[3];   // next chunk

    #pragma unroll 1
    for (int q = 0; q < NCHUNK; ++q) {
        float4 p0 = c0, p1 = c1;         // prefetch chunk q+2
        if (q + 2 < NCHUNK) { p0 = aif4[2 * q + 4]; p1 = aif4[2 * q + 5]; }
        const int base = q * 8;

#define DCE_STEP(A, U)                                                        \
        { const float a_ = (A);                                               \
          Sm  = fmaf(Sm,  rm, a_);                                            \
          Spv = fmaf(Spv, rp, a_);                                            \
          if (base + (U) == next) {      /* wave-uniform scalar branch */     \
              const float ce_   = (Sm - Spv) * inv_De;                        \
              const float cpv_  = (we * Sm + wpp * Spv) * inv_Dp;             \
              const float conc_ = vp * cpv_ + ve * ce_;                       \
              const float E_    = __expf(-0.00487f * fmaf(4.3f, conc_, 1.0f));\
              const float catr_ = M0_trans * (1.0f - E_)                      \
                                * frcp(1.0f - E_ * cos_fa);                   \
              out[s * HW_PIX + pix] = catr_ + sig_base;                       \
              ++s;                                                            \
              next = next2;                                                   \
              next2 = (s + 1 < NSAMP)                                         \
                    ? __builtin_amdgcn_readfirstlane(idx_g[s + 1]) : -1;      \
          } }

        DCE_STEP(c0.x, 0) DCE_STEP(c0.y, 1) DCE_STEP(c0.z, 2) DCE_STEP(c0.w, 3)
        DCE_STEP(c1.x, 4) DCE_STEP(c1.y, 5) DCE_STEP(c1.z, 6) DCE_STEP(c1.w, 7)
#undef DCE_STEP
        c0 = n0; c1 = n1; n0 = p0; n1 = p1;
    }
}

extern "C" void kernel_launch(void* const* d_in, const int* in_sizes, int n_in,
                              void* d_out, int out_size, void* d_ws, size_t ws_size,
                              hipStream_t stream) {
    const float* param = (const float*)d_in[0];
    const float* st    = (const float*)d_in[1];
    const float* Cp    = (const float*)d_in[2];
    float* out = (float*)d_out;

    float* aif = (float*)d_ws;                       // 592 floats
    int*   idx = (int*)((char*)d_ws + 4096);         // 50 ints

    // signal-equation constants (host double, then cast)
    double fa   = 10.0 * M_PI / 180.0;
    double cfa  = cos(fa), sfa = sin(fa);
    double E1   = exp(-0.00487);
    double M0   = 100.0 * (1.0 - cfa * E1) / (sfa * (1.0 - E1));
    double M0t  = M0 * sfa;
    double Mst  = M0t * (1.0 - E1) / (1.0 - E1 * cfa);
    float M0_trans = (float)M0t;
    float cos_fa   = (float)cfa;
    float sig_base = (float)(100.0 - Mst);

    prep_kernel<<<1, L_PAD, 0, stream>>>(st, Cp, aif, idx);
    dce_kernel<<<HW_PIX / BLK, BLK, 0, stream>>>(param, aif, idx, out,
                                                 M0_trans, cos_fa, sig_base);
}